// Round 2
// baseline (508.062 us; speedup 1.0000x reference)
//
#include <hip/hip_runtime.h>
#include <hip/hip_bf16.h>
#include <stdint.h>

typedef __bf16 bf16x8 __attribute__((ext_vector_type(8)));
typedef float  f32x4  __attribute__((ext_vector_type(4)));

#define SEQ   2048
#define DIMV  1024
#define HEADS 16
#define HDIM  64
#define KD    1024   // inner K of all projections

static __device__ __forceinline__ unsigned short f2bf(float f) {
  union { float f; unsigned u; } v; v.f = f;
  unsigned r = (v.u + 0x7fffu + ((v.u >> 16) & 1u)) >> 16;
  return (unsigned short)r;
}

// ---------------- fp32 -> bf16 convert (vectorized) ----------------
__global__ void cvt_kernel(const float* __restrict__ src,
                           ushort4* __restrict__ dst, int n4) {
  int i = blockIdx.x * 256 + threadIdx.x;
  if (i >= n4) return;
  float4 v = reinterpret_cast<const float4*>(src)[i];
  ushort4 o;
  o.x = f2bf(v.x); o.y = f2bf(v.y); o.z = f2bf(v.z); o.w = f2bf(v.w);
  dst[i] = o;
}

// ---------------- async global->LDS 16B ----------------
static __device__ __forceinline__ void gload_lds16(const unsigned short* g,
                                                   unsigned short* l) {
  __builtin_amdgcn_global_load_lds(
      (const __attribute__((address_space(1))) unsigned int*)g,
      (__attribute__((address_space(3))) unsigned int*)l, 16, 0, 0);
}

// ---------------- GEMM: C[M,N] = A[M,K] * B[N,K]^T (both K-contiguous bf16)
// MODE 0: store bf16 into q/k layout  [(b*16+h)][n][64]   (M=8192 rows=b,n ; N=1024 cols=h,d)
// MODE 1: store bf16 into Vt layout   [b][h*64+d][2048]   (M=1024 rows=d-col; N=8192 cols=b,m)
// MODE 2: store fp32 + bias to d_out  [M][N] row-major
template <int MODE>
__global__ __launch_bounds__(256) void gemm_bt(
    const unsigned short* __restrict__ A,
    const unsigned short* __restrict__ B,
    void* __restrict__ Cv,
    const float* __restrict__ bias) {
  __shared__ unsigned short As[128 * 32];
  __shared__ unsigned short Bs[128 * 32];
  const int t = threadIdx.x;
  const int lane = t & 63, wave = t >> 6;
  const int fr = lane & 15, fq = lane >> 4;
  const int m0 = blockIdx.x * 128, n0 = blockIdx.y * 128;
  const int wm0 = (wave >> 1) * 64, wn0 = (wave & 1) * 64;

  // staging map: lane l of wave w -> LDS byte w*1024 + l*16 (linear, required by global_load_lds)
  const int srow = wave * 16 + (lane >> 2);
  const int scol = (lane & 3) * 8;
  const unsigned short* gA = A + (size_t)(m0 + srow) * KD + scol;
  const unsigned short* gB = B + (size_t)(n0 + srow) * KD + scol;
  unsigned short* lA = &As[srow * 32 + scol];
  unsigned short* lB = &Bs[srow * 32 + scol];

  f32x4 acc[4][4];
#pragma unroll
  for (int i = 0; i < 4; ++i)
#pragma unroll
    for (int j = 0; j < 4; ++j) acc[i][j] = (f32x4){0.f, 0.f, 0.f, 0.f};

  for (int k0 = 0;;) {
    gload_lds16(gA + k0, lA);
    gload_lds16(gA + (size_t)64 * KD + k0, lA + 64 * 32);
    gload_lds16(gB + k0, lB);
    gload_lds16(gB + (size_t)64 * KD + k0, lB + 64 * 32);
    __syncthreads();  // drains vmcnt; tile visible

    bf16x8 af[4], bfv[4];
#pragma unroll
    for (int mi = 0; mi < 4; ++mi)
      af[mi] = *(const bf16x8*)&As[(wm0 + mi * 16 + fr) * 32 + fq * 8];
#pragma unroll
    for (int nj = 0; nj < 4; ++nj)
      bfv[nj] = *(const bf16x8*)&Bs[(wn0 + nj * 16 + fr) * 32 + fq * 8];
#pragma unroll
    for (int mi = 0; mi < 4; ++mi)
#pragma unroll
      for (int nj = 0; nj < 4; ++nj)
        acc[mi][nj] = __builtin_amdgcn_mfma_f32_16x16x32_bf16(
            af[mi], bfv[nj], acc[mi][nj], 0, 0, 0);

    k0 += 32;
    if (k0 >= KD) break;
    __syncthreads();  // all reads done before restage
  }

  // epilogue: C/D layout col = lane&15, row = (lane>>4)*4 + r
#pragma unroll
  for (int mi = 0; mi < 4; ++mi)
#pragma unroll
    for (int nj = 0; nj < 4; ++nj)
#pragma unroll
      for (int r = 0; r < 4; ++r) {
        const int gr = m0 + wm0 + mi * 16 + fq * 4 + r;
        const int gc = n0 + wn0 + nj * 16 + fr;
        const float v = acc[mi][nj][r];
        if (MODE == 0) {
          // row gr = b*2048+n ; col gc = h*64+d
          size_t off = (((size_t)(gr >> 11) * HEADS + (gc >> 6)) * SEQ +
                        (gr & 2047)) * HDIM + (gc & 63);
          ((unsigned short*)Cv)[off] = f2bf(v);
        } else if (MODE == 1) {
          // row gr = Wv row (= h*64+d) ; col gc = b*2048+m
          size_t off = (size_t)(gc >> 11) * (DIMV * SEQ) + (size_t)gr * SEQ +
                       (gc & 2047);
          ((unsigned short*)Cv)[off] = f2bf(v);
        } else {
          ((float*)Cv)[(size_t)gr * DIMV + gc] = v + bias[gc];
        }
      }
}

// ---------------- flash attention ----------------
// grid: (16 q-tiles, 64 bh). block 256 = 4 waves; wave owns 32 q rows.
// q,k: [(b*16+h)][2048][64] bf16 ; vt: [b][1024][2048] bf16
// ao : [b*2048][1024] bf16 (row-major)
__global__ __launch_bounds__(256) void attn_kernel(
    const unsigned short* __restrict__ q, const unsigned short* __restrict__ k,
    const unsigned short* __restrict__ vt, unsigned short* __restrict__ ao) {
  __shared__ unsigned short Pl[4][32 * 64];  // per-wave P tile, XOR-swizzled
  const int t = threadIdx.x, lane = t & 63, wave = t >> 6;
  const int fr = lane & 15, fq = lane >> 4;
  const int bh = blockIdx.y;
  const int b = bh >> 4, h = bh & 15;
  const int qrow0 = blockIdx.x * 128 + wave * 32;  // within this (b,h)

  const unsigned short* qp = q + ((size_t)bh * SEQ + qrow0) * HDIM;
  const unsigned short* kp = k + (size_t)bh * SEQ * HDIM;
  const unsigned short* vp = vt + (size_t)b * (DIMV * SEQ) + (size_t)(h * HDIM) * SEQ;

  // Q fragments in registers: rows mi*16+fr, k = kc*32 + fq*8
  bf16x8 qf[2][2];
#pragma unroll
  for (int mi = 0; mi < 2; ++mi)
#pragma unroll
    for (int kc = 0; kc < 2; ++kc)
      qf[mi][kc] = *(const bf16x8*)(qp + (size_t)(mi * 16 + fr) * HDIM + kc * 32 + fq * 8);

  f32x4 oacc[2][4];
  float mrow[2][4], lrow[2][4];
#pragma unroll
  for (int mi = 0; mi < 2; ++mi) {
#pragma unroll
    for (int dj = 0; dj < 4; ++dj) oacc[mi][dj] = (f32x4){0.f, 0.f, 0.f, 0.f};
#pragma unroll
    for (int r = 0; r < 4; ++r) { mrow[mi][r] = -1e30f; lrow[mi][r] = 0.f; }
  }

  for (int kb = 0; kb < SEQ; kb += 64) {
    // ---- S = Q K^T (scaled later) ----
    f32x4 sacc[2][4];
#pragma unroll
    for (int mi = 0; mi < 2; ++mi)
#pragma unroll
      for (int nj = 0; nj < 4; ++nj) sacc[mi][nj] = (f32x4){0.f, 0.f, 0.f, 0.f};

    bf16x8 kf[4][2];
#pragma unroll
    for (int nj = 0; nj < 4; ++nj)
#pragma unroll
      for (int kc = 0; kc < 2; ++kc)
        kf[nj][kc] = *(const bf16x8*)(kp + (size_t)(kb + nj * 16 + fr) * HDIM + kc * 32 + fq * 8);
#pragma unroll
    for (int mi = 0; mi < 2; ++mi)
#pragma unroll
      for (int nj = 0; nj < 4; ++nj)
#pragma unroll
        for (int kc = 0; kc < 2; ++kc)
          sacc[mi][nj] = __builtin_amdgcn_mfma_f32_16x16x32_bf16(
              qf[mi][kc], kf[nj][kc], sacc[mi][nj], 0, 0, 0);

    // ---- online softmax (rows = fq*4+r, cols spread over fr-lanes) ----
#pragma unroll
    for (int mi = 0; mi < 2; ++mi) {
      float vmax[4];
#pragma unroll
      for (int r = 0; r < 4; ++r) vmax[r] = -1e30f;
#pragma unroll
      for (int nj = 0; nj < 4; ++nj)
#pragma unroll
        for (int r = 0; r < 4; ++r) {
          sacc[mi][nj][r] *= 0.125f;  // HEAD_DIM^-0.5
          vmax[r] = fmaxf(vmax[r], sacc[mi][nj][r]);
        }
#pragma unroll
      for (int off = 8; off >= 1; off >>= 1)
#pragma unroll
        for (int r = 0; r < 4; ++r)
          vmax[r] = fmaxf(vmax[r], __shfl_xor(vmax[r], off));

      float frs[4], ls[4];
#pragma unroll
      for (int r = 0; r < 4; ++r) {
        float mn = fmaxf(mrow[mi][r], vmax[r]);
        frs[r] = __expf(mrow[mi][r] - mn);
        mrow[mi][r] = mn;
        ls[r] = 0.f;
      }
#pragma unroll
      for (int nj = 0; nj < 4; ++nj)
#pragma unroll
        for (int r = 0; r < 4; ++r) {
          float p = __expf(sacc[mi][nj][r] - mrow[mi][r]);
          ls[r] += p;
          const int row = mi * 16 + fq * 4 + r, col = nj * 16 + fr;
          Pl[wave][(row * 64 + col) ^ ((row & 7) << 3)] = f2bf(p);
        }
#pragma unroll
      for (int off = 8; off >= 1; off >>= 1)
#pragma unroll
        for (int r = 0; r < 4; ++r) ls[r] += __shfl_xor(ls[r], off);
#pragma unroll
      for (int r = 0; r < 4; ++r) lrow[mi][r] = lrow[mi][r] * frs[r] + ls[r];
#pragma unroll
      for (int dj = 0; dj < 4; ++dj)
#pragma unroll
        for (int r = 0; r < 4; ++r) oacc[mi][dj][r] *= frs[r];
    }

    // ---- O += P V  (A = P from LDS, B = Vt streamed) ----
    bf16x8 pf[2][2], vf[4][2];
#pragma unroll
    for (int mi = 0; mi < 2; ++mi)
#pragma unroll
      for (int kc = 0; kc < 2; ++kc) {
        const int row = mi * 16 + fr, col = kc * 32 + fq * 8;
        pf[mi][kc] = *(const bf16x8*)&Pl[wave][(row * 64 + col) ^ ((row & 7) << 3)];
      }
#pragma unroll
    for (int dj = 0; dj < 4; ++dj)
#pragma unroll
      for (int kc = 0; kc < 2; ++kc)
        vf[dj][kc] = *(const bf16x8*)(vp + (size_t)(dj * 16 + fr) * SEQ + kb + kc * 32 + fq * 8);
#pragma unroll
    for (int mi = 0; mi < 2; ++mi)
#pragma unroll
      for (int dj = 0; dj < 4; ++dj)
#pragma unroll
        for (int kc = 0; kc < 2; ++kc)
          oacc[mi][dj] = __builtin_amdgcn_mfma_f32_16x16x32_bf16(
              pf[mi][kc], vf[dj][kc], oacc[mi][dj], 0, 0, 0);
  }

  // ---- normalize + store (row-major ao[b*2048+n][h*64+d]) ----
#pragma unroll
  for (int mi = 0; mi < 2; ++mi)
#pragma unroll
    for (int dj = 0; dj < 4; ++dj)
#pragma unroll
      for (int r = 0; r < 4; ++r) {
        const size_t grow = (size_t)b * SEQ + blockIdx.x * 128 + wave * 32 + mi * 16 + fq * 4 + r;
        const int col = h * HDIM + dj * 16 + fr;
        ao[grow * DIMV + col] = f2bf(oacc[mi][dj][r] / lrow[mi][r]);
      }
}

// ---------------- launch ----------------
extern "C" void kernel_launch(void* const* d_in, const int* in_sizes, int n_in,
                              void* d_out, int out_size, void* d_ws, size_t ws_size,
                              hipStream_t stream) {
  const float* x   = (const float*)d_in[0];
  const float* ctx = (const float*)d_in[1];
  const float* Wq  = (const float*)d_in[2];
  const float* Wk  = (const float*)d_in[3];
  const float* Wv  = (const float*)d_in[4];
  const float* Wo  = (const float*)d_in[5];
  const float* bo  = (const float*)d_in[6];

  char* ws = (char*)d_ws;
  unsigned short* xb  = (unsigned short*)(ws);              // 16MB, reused as ao
  unsigned short* cb  = (unsigned short*)(ws + 16777216);   // 16MB
  unsigned short* wqb = (unsigned short*)(ws + 33554432);   // 2MB
  unsigned short* wkb = (unsigned short*)(ws + 35651584);
  unsigned short* wvb = (unsigned short*)(ws + 37748736);
  unsigned short* wob = (unsigned short*)(ws + 39845888);
  unsigned short* qb  = (unsigned short*)(ws + 41943040);   // 16MB
  unsigned short* kb  = (unsigned short*)(ws + 58720256);   // 16MB
  unsigned short* vtb = (unsigned short*)(ws + 75497472);   // 16MB

  auto cvt = [&](const float* s, unsigned short* d, int n) {
    int n4 = n >> 2;
    cvt_kernel<<<(n4 + 255) / 256, 256, 0, stream>>>(s, (ushort4*)d, n4);
  };
  const int NTOK = 4 * SEQ;  // 8192
  cvt(x,   xb,  NTOK * DIMV);
  cvt(ctx, cb,  NTOK * DIMV);
  cvt(Wq,  wqb, DIMV * DIMV);
  cvt(Wk,  wkb, DIMV * DIMV);
  cvt(Wv,  wvb, DIMV * DIMV);
  cvt(Wo,  wob, DIMV * DIMV);

  // Q = x Wq^T   (M=8192, N=1024)
  gemm_bt<0><<<dim3(64, 8), 256, 0, stream>>>(xb, wqb, qb, nullptr);
  // K = ctx Wk^T (M=8192, N=1024)
  gemm_bt<0><<<dim3(64, 8), 256, 0, stream>>>(cb, wkb, kb, nullptr);
  // Vt = Wv ctx^T (M=1024, N=8192)
  gemm_bt<1><<<dim3(8, 64), 256, 0, stream>>>(wvb, cb, vtb, nullptr);

  // attention -> ao (reuses xb region)
  unsigned short* aob = xb;
  attn_kernel<<<dim3(16, 64), 256, 0, stream>>>(qb, kb, vtb, aob);

  // out = ao Wo^T + bo (fp32)
  gemm_bt<2><<<dim3(64, 8), 256, 0, stream>>>(aob, wob, (float*)d_out, bo);
}

// Round 3
// 485.049 us; speedup vs baseline: 1.0474x; 1.0474x over previous
//
#include <hip/hip_runtime.h>
#include <hip/hip_bf16.h>
#include <stdint.h>

typedef __bf16 bf16x8 __attribute__((ext_vector_type(8)));
typedef float  f32x4  __attribute__((ext_vector_type(4)));

#define SEQ   2048
#define DIMV  1024
#define HEADS 16
#define HDIM  64
#define KD    1024   // inner K of all projections

// 0.125 (HEAD_DIM^-0.5) * log2(e)
#define SCL 0.1803368801111204f

static __device__ __forceinline__ unsigned short f2bf(float f) {
  union { float f; unsigned u; } v; v.f = f;
  unsigned r = (v.u + 0x7fffu + ((v.u >> 16) & 1u)) >> 16;
  return (unsigned short)r;
}

// ---------------- fp32 -> bf16 convert (vectorized) ----------------
__global__ void cvt_kernel(const float* __restrict__ src,
                           ushort4* __restrict__ dst, int n4) {
  int i = blockIdx.x * 256 + threadIdx.x;
  if (i >= n4) return;
  float4 v = reinterpret_cast<const float4*>(src)[i];
  ushort4 o;
  o.x = f2bf(v.x); o.y = f2bf(v.y); o.z = f2bf(v.z); o.w = f2bf(v.w);
  dst[i] = o;
}

// ---------------- async global->LDS 16B ----------------
static __device__ __forceinline__ void gload_lds16(const unsigned short* g,
                                                   unsigned short* l) {
  __builtin_amdgcn_global_load_lds(
      (const __attribute__((address_space(1))) unsigned int*)g,
      (__attribute__((address_space(3))) unsigned int*)l, 16, 0, 0);
}

// ---------------- GEMM: C[M,N] = A[M,K] * B[N,K]^T (both K-contiguous bf16)
// MODE 0: store bf16 into q/k layout  [(b*16+h)][n][64]
// MODE 1: store bf16 into Vt layout   [b][h*64+d][2048]
// MODE 2: store fp32 + bias to d_out  [M][N] row-major
template <int MODE>
__global__ __launch_bounds__(256) void gemm_bt(
    const unsigned short* __restrict__ A,
    const unsigned short* __restrict__ B,
    void* __restrict__ Cv,
    const float* __restrict__ bias) {
  __shared__ unsigned short As[128 * 32];
  __shared__ unsigned short Bs[128 * 32];
  const int t = threadIdx.x;
  const int lane = t & 63, wave = t >> 6;
  const int fr = lane & 15, fq = lane >> 4;
  const int m0 = blockIdx.x * 128, n0 = blockIdx.y * 128;
  const int wm0 = (wave >> 1) * 64, wn0 = (wave & 1) * 64;

  const int srow = wave * 16 + (lane >> 2);
  const int scol = (lane & 3) * 8;
  const unsigned short* gA = A + (size_t)(m0 + srow) * KD + scol;
  const unsigned short* gB = B + (size_t)(n0 + srow) * KD + scol;
  unsigned short* lA = &As[srow * 32 + scol];
  unsigned short* lB = &Bs[srow * 32 + scol];

  f32x4 acc[4][4];
#pragma unroll
  for (int i = 0; i < 4; ++i)
#pragma unroll
    for (int j = 0; j < 4; ++j) acc[i][j] = (f32x4){0.f, 0.f, 0.f, 0.f};

  for (int k0 = 0;;) {
    gload_lds16(gA + k0, lA);
    gload_lds16(gA + (size_t)64 * KD + k0, lA + 64 * 32);
    gload_lds16(gB + k0, lB);
    gload_lds16(gB + (size_t)64 * KD + k0, lB + 64 * 32);
    __syncthreads();

    bf16x8 af[4], bfv[4];
#pragma unroll
    for (int mi = 0; mi < 4; ++mi)
      af[mi] = *(const bf16x8*)&As[(wm0 + mi * 16 + fr) * 32 + fq * 8];
#pragma unroll
    for (int nj = 0; nj < 4; ++nj)
      bfv[nj] = *(const bf16x8*)&Bs[(wn0 + nj * 16 + fr) * 32 + fq * 8];
#pragma unroll
    for (int mi = 0; mi < 4; ++mi)
#pragma unroll
      for (int nj = 0; nj < 4; ++nj)
        acc[mi][nj] = __builtin_amdgcn_mfma_f32_16x16x32_bf16(
            af[mi], bfv[nj], acc[mi][nj], 0, 0, 0);

    k0 += 32;
    if (k0 >= KD) break;
    __syncthreads();
  }

#pragma unroll
  for (int mi = 0; mi < 4; ++mi)
#pragma unroll
    for (int nj = 0; nj < 4; ++nj)
#pragma unroll
      for (int r = 0; r < 4; ++r) {
        const int gr = m0 + wm0 + mi * 16 + fq * 4 + r;
        const int gc = n0 + wn0 + nj * 16 + fr;
        const float v = acc[mi][nj][r];
        if (MODE == 0) {
          size_t off = (((size_t)(gr >> 11) * HEADS + (gc >> 6)) * SEQ +
                        (gr & 2047)) * HDIM + (gc & 63);
          ((unsigned short*)Cv)[off] = f2bf(v);
        } else if (MODE == 1) {
          size_t off = (size_t)(gc >> 11) * (DIMV * SEQ) + (size_t)gr * SEQ +
                       (gc & 2047);
          ((unsigned short*)Cv)[off] = f2bf(v);
        } else {
          ((float*)Cv)[(size_t)gr * DIMV + gc] = v + bias[gc];
        }
      }
}

// ---------------- flash attention (swapped-QK^T, lane-local softmax) -------
// grid: (16 q-tiles, 64 bh). block 256 = 4 waves; wave owns 32 q rows.
// q,k: [(b*16+h)][2048][64] bf16 ; vt: [b][1024][2048] bf16
// ao : [b*2048][1024] bf16 (row-major)
__global__ __launch_bounds__(256) void attn_kernel(
    const unsigned short* __restrict__ q, const unsigned short* __restrict__ k,
    const unsigned short* __restrict__ vt, unsigned short* __restrict__ ao) {
  __shared__ unsigned short Pl[4][32 * 64];  // per-wave P tile, XOR-swizzled
  const int t = threadIdx.x, lane = t & 63, wave = t >> 6;
  const int fr = lane & 15, fq = lane >> 4;
  const int bh = blockIdx.y;
  const int b = bh >> 4, h = bh & 15;
  const int qrow0 = blockIdx.x * 128 + wave * 32;

  const unsigned short* qp = q + ((size_t)bh * SEQ + qrow0) * HDIM;
  const unsigned short* kp = k + (size_t)bh * SEQ * HDIM;
  const unsigned short* vp = vt + (size_t)b * (DIMV * SEQ) + (size_t)(h * HDIM) * SEQ;
  char* plw = (char*)&Pl[wave][0];

  // Q fragments: rows mi*16+fr, d = kc*32 + fq*8
  bf16x8 qf[2][2];
#pragma unroll
  for (int mi = 0; mi < 2; ++mi)
#pragma unroll
    for (int kc = 0; kc < 2; ++kc)
      qf[mi][kc] = *(const bf16x8*)(qp + (size_t)(mi * 16 + fr) * HDIM + kc * 32 + fq * 8);

  f32x4 oacc[2][4];
  float m_s[2], m_o[2][4], lrow[2];
#pragma unroll
  for (int mi = 0; mi < 2; ++mi) {
#pragma unroll
    for (int dj = 0; dj < 4; ++dj) oacc[mi][dj] = (f32x4){0.f, 0.f, 0.f, 0.f};
    m_s[mi] = -1e30f; lrow[mi] = 0.f;
#pragma unroll
    for (int r = 0; r < 4; ++r) m_o[mi][r] = -1e30f;
  }

  for (int kb = 0; kb < SEQ; kb += 64) {
    // ---- S^T-ish: sacc[mi][nj] = mfma(K, Q) ->
    //      sacc[mi][nj][r] = S[q = mi*16+fr][k = kb + nj*16 + fq*4 + r] (raw)
    f32x4 sacc[2][4];
#pragma unroll
    for (int mi = 0; mi < 2; ++mi)
#pragma unroll
      for (int nj = 0; nj < 4; ++nj) sacc[mi][nj] = (f32x4){0.f, 0.f, 0.f, 0.f};

    bf16x8 kf[4][2];
#pragma unroll
    for (int nj = 0; nj < 4; ++nj)
#pragma unroll
      for (int kc = 0; kc < 2; ++kc)
        kf[nj][kc] = *(const bf16x8*)(kp + (size_t)(kb + nj * 16 + fr) * HDIM + kc * 32 + fq * 8);
#pragma unroll
    for (int mi = 0; mi < 2; ++mi)
#pragma unroll
      for (int nj = 0; nj < 4; ++nj)
#pragma unroll
        for (int kc = 0; kc < 2; ++kc)
          sacc[mi][nj] = __builtin_amdgcn_mfma_f32_16x16x32_bf16(
              kf[nj][kc], qf[mi][kc], sacc[mi][nj], 0, 0, 0);

    // ---- online softmax: each lane owns one q-row per mi ----
#pragma unroll
    for (int mi = 0; mi < 2; ++mi) {
      float tmax = -1e30f;
#pragma unroll
      for (int nj = 0; nj < 4; ++nj)
#pragma unroll
        for (int r = 0; r < 4; ++r) tmax = fmaxf(tmax, sacc[mi][nj][r]);
      tmax = fmaxf(tmax, __shfl_xor(tmax, 16));
      tmax = fmaxf(tmax, __shfl_xor(tmax, 32));

      if (__any(tmax > m_s[mi])) {
        const float mnew = fmaxf(m_s[mi], tmax);
        lrow[mi] *= exp2f((m_s[mi] - mnew) * SCL);
        m_s[mi] = mnew;
#pragma unroll
        for (int r = 0; r < 4; ++r) {
          const float t_o = __shfl(tmax, ((lane >> 4) << 2) + r);
          const float mo_new = fmaxf(m_o[mi][r], t_o);
          const float fo = exp2f((m_o[mi][r] - mo_new) * SCL);
          m_o[mi][r] = mo_new;
#pragma unroll
          for (int dj = 0; dj < 4; ++dj) oacc[mi][dj][r] *= fo;
        }
      }

      float ls = 0.f;
      const int row = mi * 16 + fr;
#pragma unroll
      for (int nj = 0; nj < 4; ++nj) {
        float p0 = exp2f((sacc[mi][nj][0] - m_s[mi]) * SCL);
        float p1 = exp2f((sacc[mi][nj][1] - m_s[mi]) * SCL);
        float p2 = exp2f((sacc[mi][nj][2] - m_s[mi]) * SCL);
        float p3 = exp2f((sacc[mi][nj][3] - m_s[mi]) * SCL);
        ls += (p0 + p1) + (p2 + p3);
        unsigned lo = (unsigned)f2bf(p0) | ((unsigned)f2bf(p1) << 16);
        unsigned hi = (unsigned)f2bf(p2) | ((unsigned)f2bf(p3) << 16);
        const int colb = (nj * 16 + fq * 4) * 2;
        *(uint2*)(plw + ((row * 128 + colb) ^ ((row & 7) << 4))) =
            make_uint2(lo, hi);
      }
      lrow[mi] += ls;
    }

    // ---- O += P V ----
    bf16x8 pf[2][2], vf[4][2];
#pragma unroll
    for (int mi = 0; mi < 2; ++mi)
#pragma unroll
      for (int kc = 0; kc < 2; ++kc) {
        const int row = mi * 16 + fr, colb = (kc * 32 + fq * 8) * 2;
        pf[mi][kc] = *(const bf16x8*)(plw + ((row * 128 + colb) ^ ((row & 7) << 4)));
      }
#pragma unroll
    for (int dj = 0; dj < 4; ++dj)
#pragma unroll
      for (int kc = 0; kc < 2; ++kc)
        vf[dj][kc] = *(const bf16x8*)(vp + (size_t)(dj * 16 + fr) * SEQ + kb + kc * 32 + fq * 8);
#pragma unroll
    for (int mi = 0; mi < 2; ++mi)
#pragma unroll
      for (int dj = 0; dj < 4; ++dj)
#pragma unroll
        for (int kc = 0; kc < 2; ++kc)
          oacc[mi][dj] = __builtin_amdgcn_mfma_f32_16x16x32_bf16(
              pf[mi][kc], vf[dj][kc], oacc[mi][dj], 0, 0, 0);
  }

  // ---- final l reduce + redistribute to O-layout, normalize + store ----
#pragma unroll
  for (int mi = 0; mi < 2; ++mi) {
    float lt = lrow[mi];
    lt += __shfl_xor(lt, 16);
    lt += __shfl_xor(lt, 32);
#pragma unroll
    for (int r = 0; r < 4; ++r) {
      const float l_o = __shfl(lt, ((lane >> 4) << 2) + r);
      const float inv = 1.f / l_o;
      const size_t grow = (size_t)b * SEQ + blockIdx.x * 128 + wave * 32 +
                          mi * 16 + fq * 4 + r;
#pragma unroll
      for (int dj = 0; dj < 4; ++dj) {
        const int col = h * HDIM + dj * 16 + fr;
        ao[grow * DIMV + col] = f2bf(oacc[mi][dj][r] * inv);
      }
    }
  }
}

// ---------------- launch ----------------
extern "C" void kernel_launch(void* const* d_in, const int* in_sizes, int n_in,
                              void* d_out, int out_size, void* d_ws, size_t ws_size,
                              hipStream_t stream) {
  const float* x   = (const float*)d_in[0];
  const float* ctx = (const float*)d_in[1];
  const float* Wq  = (const float*)d_in[2];
  const float* Wk  = (const float*)d_in[3];
  const float* Wv  = (const float*)d_in[4];
  const float* Wo  = (const float*)d_in[5];
  const float* bo  = (const float*)d_in[6];

  char* ws = (char*)d_ws;
  unsigned short* xb  = (unsigned short*)(ws);              // 16MB, reused as ao
  unsigned short* cb  = (unsigned short*)(ws + 16777216);   // 16MB
  unsigned short* wqb = (unsigned short*)(ws + 33554432);   // 2MB
  unsigned short* wkb = (unsigned short*)(ws + 35651584);
  unsigned short* wvb = (unsigned short*)(ws + 37748736);
  unsigned short* wob = (unsigned short*)(ws + 39845888);
  unsigned short* qb  = (unsigned short*)(ws + 41943040);   // 16MB
  unsigned short* kb  = (unsigned short*)(ws + 58720256);   // 16MB
  unsigned short* vtb = (unsigned short*)(ws + 75497472);   // 16MB

  auto cvt = [&](const float* s, unsigned short* d, int n) {
    int n4 = n >> 2;
    cvt_kernel<<<(n4 + 255) / 256, 256, 0, stream>>>(s, (ushort4*)d, n4);
  };
  const int NTOK = 4 * SEQ;  // 8192
  cvt(x,   xb,  NTOK * DIMV);
  cvt(ctx, cb,  NTOK * DIMV);
  cvt(Wq,  wqb, DIMV * DIMV);
  cvt(Wk,  wkb, DIMV * DIMV);
  cvt(Wv,  wvb, DIMV * DIMV);
  cvt(Wo,  wob, DIMV * DIMV);

  // Q = x Wq^T   (M=8192, N=1024)
  gemm_bt<0><<<dim3(64, 8), 256, 0, stream>>>(xb, wqb, qb, nullptr);
  // K = ctx Wk^T (M=8192, N=1024)
  gemm_bt<0><<<dim3(64, 8), 256, 0, stream>>>(cb, wkb, kb, nullptr);
  // Vt = Wv ctx^T (M=1024, N=8192)
  gemm_bt<1><<<dim3(8, 64), 256, 0, stream>>>(wvb, cb, vtb, nullptr);

  // attention -> ao (reuses xb region)
  unsigned short* aob = xb;
  attn_kernel<<<dim3(16, 64), 256, 0, stream>>>(qb, kb, vtb, aob);

  // out = ao Wo^T + bo (fp32)
  gemm_bt<2><<<dim3(64, 8), 256, 0, stream>>>(aob, wob, (float*)d_out, bo);
}

// Round 4
// 475.669 us; speedup vs baseline: 1.0681x; 1.0197x over previous
//
#include <hip/hip_runtime.h>
#include <hip/hip_bf16.h>
#include <stdint.h>

typedef __bf16 bf16x8 __attribute__((ext_vector_type(8)));
typedef float  f32x4  __attribute__((ext_vector_type(4)));

#define SEQ   2048
#define DIMV  1024
#define HEADS 16
#define HDIM  64
#define KD    1024

// 0.125 (HEAD_DIM^-0.5) * log2(e)
#define SCL 0.1803368801111204f
// defer-max threshold in raw-score units: THR*SCL = 8 -> P <= 2^8
#define THRRAW 44.36f

static __device__ __forceinline__ unsigned short f2bf(float f) {
  union { float f; unsigned u; } v; v.f = f;
  unsigned r = (v.u + 0x7fffu + ((v.u >> 16) & 1u)) >> 16;
  return (unsigned short)r;
}

static __device__ __forceinline__ unsigned cvtpk(float a, float b) {
  unsigned r;
  asm("v_cvt_pk_bf16_f32 %0, %1, %2" : "=v"(r) : "v"(a), "v"(b));
  return r;  // low16 = bf16(a), high16 = bf16(b)
}

// ---------------- fp32 -> bf16 convert (vectorized) ----------------
__global__ void cvt_kernel(const float* __restrict__ src,
                           ushort4* __restrict__ dst, int n4) {
  int i = blockIdx.x * 256 + threadIdx.x;
  if (i >= n4) return;
  float4 v = reinterpret_cast<const float4*>(src)[i];
  ushort4 o;
  o.x = f2bf(v.x); o.y = f2bf(v.y); o.z = f2bf(v.z); o.w = f2bf(v.w);
  dst[i] = o;
}

// ---------------- async global->LDS 16B ----------------
static __device__ __forceinline__ void gload_lds16(const unsigned short* g,
                                                   unsigned short* l) {
  __builtin_amdgcn_global_load_lds(
      (const __attribute__((address_space(1))) unsigned int*)g,
      (__attribute__((address_space(3))) unsigned int*)l, 16, 0, 0);
}

// ---------------- GEMM: C[M,N] = A[M,K] * B[N,K]^T ----------------
template <int MODE>
__global__ __launch_bounds__(256) void gemm_bt(
    const unsigned short* __restrict__ A,
    const unsigned short* __restrict__ B,
    void* __restrict__ Cv,
    const float* __restrict__ bias) {
  __shared__ unsigned short As[128 * 32];
  __shared__ unsigned short Bs[128 * 32];
  const int t = threadIdx.x;
  const int lane = t & 63, wave = t >> 6;
  const int fr = lane & 15, fq = lane >> 4;
  const int m0 = blockIdx.x * 128, n0 = blockIdx.y * 128;
  const int wm0 = (wave >> 1) * 64, wn0 = (wave & 1) * 64;

  const int srow = wave * 16 + (lane >> 2);
  const int scol = (lane & 3) * 8;
  const unsigned short* gA = A + (size_t)(m0 + srow) * KD + scol;
  const unsigned short* gB = B + (size_t)(n0 + srow) * KD + scol;
  unsigned short* lA = &As[srow * 32 + scol];
  unsigned short* lB = &Bs[srow * 32 + scol];

  f32x4 acc[4][4];
#pragma unroll
  for (int i = 0; i < 4; ++i)
#pragma unroll
    for (int j = 0; j < 4; ++j) acc[i][j] = (f32x4){0.f, 0.f, 0.f, 0.f};

  for (int k0 = 0;;) {
    gload_lds16(gA + k0, lA);
    gload_lds16(gA + (size_t)64 * KD + k0, lA + 64 * 32);
    gload_lds16(gB + k0, lB);
    gload_lds16(gB + (size_t)64 * KD + k0, lB + 64 * 32);
    __syncthreads();

    bf16x8 af[4], bfv[4];
#pragma unroll
    for (int mi = 0; mi < 4; ++mi)
      af[mi] = *(const bf16x8*)&As[(wm0 + mi * 16 + fr) * 32 + fq * 8];
#pragma unroll
    for (int nj = 0; nj < 4; ++nj)
      bfv[nj] = *(const bf16x8*)&Bs[(wn0 + nj * 16 + fr) * 32 + fq * 8];
#pragma unroll
    for (int mi = 0; mi < 4; ++mi)
#pragma unroll
      for (int nj = 0; nj < 4; ++nj)
        acc[mi][nj] = __builtin_amdgcn_mfma_f32_16x16x32_bf16(
            af[mi], bfv[nj], acc[mi][nj], 0, 0, 0);

    k0 += 32;
    if (k0 >= KD) break;
    __syncthreads();
  }

#pragma unroll
  for (int mi = 0; mi < 4; ++mi)
#pragma unroll
    for (int nj = 0; nj < 4; ++nj)
#pragma unroll
      for (int r = 0; r < 4; ++r) {
        const int gr = m0 + wm0 + mi * 16 + fq * 4 + r;
        const int gc = n0 + wn0 + nj * 16 + fr;
        const float v = acc[mi][nj][r];
        if (MODE == 0) {
          size_t off = (((size_t)(gr >> 11) * HEADS + (gc >> 6)) * SEQ +
                        (gr & 2047)) * HDIM + (gc & 63);
          ((unsigned short*)Cv)[off] = f2bf(v);
        } else if (MODE == 1) {
          size_t off = (size_t)(gc >> 11) * (DIMV * SEQ) + (size_t)gr * SEQ +
                       (gc & 2047);
          ((unsigned short*)Cv)[off] = f2bf(v);
        } else {
          ((float*)Cv)[(size_t)gr * DIMV + gc] = v + bias[gc];
        }
      }
}

// ---------------- flash attention ----------------
// grid (16 qtiles, 64 bh), 4 waves; wave owns 32 q rows, streams all 2048 keys.
// Swapped QK^T: S lanes hold q at fr, k at fq*4+r -> lane-local softmax.
// Swapped PV:   O lanes hold q at fr, d at fq*4+r -> lane-local rescale/norm.
__global__ __launch_bounds__(256, 3) void attn_kernel(
    const unsigned short* __restrict__ q, const unsigned short* __restrict__ k,
    const unsigned short* __restrict__ vt, unsigned short* __restrict__ ao) {
  __shared__ unsigned short Pl[4][32 * 64];
  const int t = threadIdx.x, lane = t & 63, wave = t >> 6;
  const int fr = lane & 15, fq = lane >> 4;
  const int bh = blockIdx.y;
  const int b = bh >> 4, h = bh & 15;
  const int qrow0 = blockIdx.x * 128 + wave * 32;

  const unsigned short* qp = q + ((size_t)bh * SEQ + qrow0) * HDIM;
  const unsigned short* kp = k + (size_t)bh * SEQ * HDIM;
  const unsigned short* vp = vt + (size_t)b * (DIMV * SEQ) + (size_t)(h * HDIM) * SEQ;
  char* plw = (char*)&Pl[wave][0];

  bf16x8 qf[2][2];
#pragma unroll
  for (int mi = 0; mi < 2; ++mi)
#pragma unroll
    for (int kc = 0; kc < 2; ++kc)
      qf[mi][kc] = *(const bf16x8*)(qp + (size_t)(mi * 16 + fr) * HDIM + kc * 32 + fq * 8);

  f32x4 oacc[2][4];
  float m_s[2], lrow[2];
#pragma unroll
  for (int mi = 0; mi < 2; ++mi) {
#pragma unroll
    for (int dj = 0; dj < 4; ++dj) oacc[mi][dj] = (f32x4){0.f, 0.f, 0.f, 0.f};
    m_s[mi] = -1e30f; lrow[mi] = 0.f;
  }

  for (int kb = 0; kb < SEQ; kb += 64) {
    // ---- issue all K and V loads up front (V latency hides under QK+softmax)
    bf16x8 kf[4][2], vf[4][2];
#pragma unroll
    for (int nj = 0; nj < 4; ++nj)
#pragma unroll
      for (int kc = 0; kc < 2; ++kc)
        kf[nj][kc] = *(const bf16x8*)(kp + (size_t)(kb + nj * 16 + fr) * HDIM + kc * 32 + fq * 8);
#pragma unroll
    for (int dj = 0; dj < 4; ++dj)
#pragma unroll
      for (int kc = 0; kc < 2; ++kc)
        vf[dj][kc] = *(const bf16x8*)(vp + (size_t)(dj * 16 + fr) * SEQ + kb + kc * 32 + fq * 8);

    // ---- S = mfma(K, Q): lane holds S[q=mi*16+fr][k=nj*16+fq*4+r]
    f32x4 sacc[2][4];
#pragma unroll
    for (int mi = 0; mi < 2; ++mi)
#pragma unroll
      for (int nj = 0; nj < 4; ++nj) sacc[mi][nj] = (f32x4){0.f, 0.f, 0.f, 0.f};
    __builtin_amdgcn_s_setprio(1);
#pragma unroll
    for (int mi = 0; mi < 2; ++mi)
#pragma unroll
      for (int nj = 0; nj < 4; ++nj)
#pragma unroll
        for (int kc = 0; kc < 2; ++kc)
          sacc[mi][nj] = __builtin_amdgcn_mfma_f32_16x16x32_bf16(
              kf[nj][kc], qf[mi][kc], sacc[mi][nj], 0, 0, 0);
    __builtin_amdgcn_s_setprio(0);

    // ---- softmax, lane-local per q-row ----
#pragma unroll
    for (int mi = 0; mi < 2; ++mi) {
      float t0 = fmaxf(fmaxf(sacc[mi][0][0], sacc[mi][0][1]),
                       fmaxf(sacc[mi][0][2], sacc[mi][0][3]));
      float t1 = fmaxf(fmaxf(sacc[mi][1][0], sacc[mi][1][1]),
                       fmaxf(sacc[mi][1][2], sacc[mi][1][3]));
      float t2 = fmaxf(fmaxf(sacc[mi][2][0], sacc[mi][2][1]),
                       fmaxf(sacc[mi][2][2], sacc[mi][2][3]));
      float t3 = fmaxf(fmaxf(sacc[mi][3][0], sacc[mi][3][1]),
                       fmaxf(sacc[mi][3][2], sacc[mi][3][3]));
      float tmax = fmaxf(fmaxf(t0, t1), fmaxf(t2, t3));
      tmax = fmaxf(tmax, __shfl_xor(tmax, 16));
      tmax = fmaxf(tmax, __shfl_xor(tmax, 32));

      if (__any(tmax > m_s[mi] + THRRAW)) {       // T13 defer-max
        const float mnew = fmaxf(m_s[mi], tmax);
        const float fo = exp2f((m_s[mi] - mnew) * SCL);
        m_s[mi] = mnew;
        lrow[mi] *= fo;
#pragma unroll
        for (int dj = 0; dj < 4; ++dj)
#pragma unroll
          for (int r = 0; r < 4; ++r) oacc[mi][dj][r] *= fo;
      }

      const float nm = m_s[mi] * SCL;
      const int row = mi * 16 + fr;
      float lacc = 0.f;
#pragma unroll
      for (int nj = 0; nj < 4; ++nj) {
        float p0 = exp2f(__builtin_fmaf(sacc[mi][nj][0], SCL, -nm));
        float p1 = exp2f(__builtin_fmaf(sacc[mi][nj][1], SCL, -nm));
        float p2 = exp2f(__builtin_fmaf(sacc[mi][nj][2], SCL, -nm));
        float p3 = exp2f(__builtin_fmaf(sacc[mi][nj][3], SCL, -nm));
        lacc += (p0 + p1) + (p2 + p3);
        unsigned w0 = cvtpk(p0, p1);
        unsigned w1 = cvtpk(p2, p3);
        const int colb = (nj * 16 + fq * 4) * 2;
        *(uint2*)(plw + ((row * 128 + colb) ^ ((row & 7) << 4))) =
            make_uint2(w0, w1);
      }
      lrow[mi] += lacc;
    }

    // ---- O += (P V) computed as mfma(V, P): q stays at fr ----
    bf16x8 pf[2][2];
#pragma unroll
    for (int mi = 0; mi < 2; ++mi)
#pragma unroll
      for (int kc = 0; kc < 2; ++kc) {
        const int row = mi * 16 + fr, colb = (kc * 32 + fq * 8) * 2;
        pf[mi][kc] = *(const bf16x8*)(plw + ((row * 128 + colb) ^ ((row & 7) << 4)));
      }
    __builtin_amdgcn_s_setprio(1);
#pragma unroll
    for (int mi = 0; mi < 2; ++mi)
#pragma unroll
      for (int dj = 0; dj < 4; ++dj)
#pragma unroll
        for (int kc = 0; kc < 2; ++kc)
          oacc[mi][dj] = __builtin_amdgcn_mfma_f32_16x16x32_bf16(
              vf[dj][kc], pf[mi][kc], oacc[mi][dj], 0, 0, 0);
    __builtin_amdgcn_s_setprio(0);
  }

  // ---- final: row-sum across fq groups, lane-local normalize, packed store
#pragma unroll
  for (int mi = 0; mi < 2; ++mi) {
    float lt = lrow[mi];
    lt += __shfl_xor(lt, 16);
    lt += __shfl_xor(lt, 32);
    const float inv = 1.f / lt;
    const size_t grow = (size_t)b * SEQ + blockIdx.x * 128 + wave * 32 + mi * 16 + fr;
#pragma unroll
    for (int dj = 0; dj < 4; ++dj) {
      unsigned w0 = cvtpk(oacc[mi][dj][0] * inv, oacc[mi][dj][1] * inv);
      unsigned w1 = cvtpk(oacc[mi][dj][2] * inv, oacc[mi][dj][3] * inv);
      const int col = h * HDIM + dj * 16 + fq * 4;
      *(uint2*)&ao[grow * DIMV + col] = make_uint2(w0, w1);
    }
  }
}

// ---------------- launch ----------------
extern "C" void kernel_launch(void* const* d_in, const int* in_sizes, int n_in,
                              void* d_out, int out_size, void* d_ws, size_t ws_size,
                              hipStream_t stream) {
  const float* x   = (const float*)d_in[0];
  const float* ctx = (const float*)d_in[1];
  const float* Wq  = (const float*)d_in[2];
  const float* Wk  = (const float*)d_in[3];
  const float* Wv  = (const float*)d_in[4];
  const float* Wo  = (const float*)d_in[5];
  const float* bo  = (const float*)d_in[6];

  char* ws = (char*)d_ws;
  unsigned short* xb  = (unsigned short*)(ws);              // 16MB, reused as ao
  unsigned short* cb  = (unsigned short*)(ws + 16777216);   // 16MB
  unsigned short* wqb = (unsigned short*)(ws + 33554432);   // 2MB
  unsigned short* wkb = (unsigned short*)(ws + 35651584);
  unsigned short* wvb = (unsigned short*)(ws + 37748736);
  unsigned short* wob = (unsigned short*)(ws + 39845888);
  unsigned short* qb  = (unsigned short*)(ws + 41943040);   // 16MB
  unsigned short* kb  = (unsigned short*)(ws + 58720256);   // 16MB
  unsigned short* vtb = (unsigned short*)(ws + 75497472);   // 16MB

  auto cvt = [&](const float* s, unsigned short* d, int n) {
    int n4 = n >> 2;
    cvt_kernel<<<(n4 + 255) / 256, 256, 0, stream>>>(s, (ushort4*)d, n4);
  };
  const int NTOK = 4 * SEQ;  // 8192
  cvt(x,   xb,  NTOK * DIMV);
  cvt(ctx, cb,  NTOK * DIMV);
  cvt(Wq,  wqb, DIMV * DIMV);
  cvt(Wk,  wkb, DIMV * DIMV);
  cvt(Wv,  wvb, DIMV * DIMV);
  cvt(Wo,  wob, DIMV * DIMV);

  gemm_bt<0><<<dim3(64, 8), 256, 0, stream>>>(xb, wqb, qb, nullptr);
  gemm_bt<0><<<dim3(64, 8), 256, 0, stream>>>(cb, wkb, kb, nullptr);
  gemm_bt<1><<<dim3(8, 64), 256, 0, stream>>>(wvb, cb, vtb, nullptr);

  unsigned short* aob = xb;
  attn_kernel<<<dim3(16, 64), 256, 0, stream>>>(qb, kb, vtb, aob);

  gemm_bt<2><<<dim3(64, 8), 256, 0, stream>>>(aob, wob, (float*)d_out, bo);
}